// Round 6
// baseline (337.740 us; speedup 1.0000x reference)
//
#include <hip/hip_runtime.h>
#include <hip/hip_bf16.h>
#include <stdint.h>

// CRF entity layer: B=64, T=512, H=768, K=32
//   1) gemm_pot: pot[b][t][k] = x[b,t,:]·W[:,k] + b[k]
//   2) scan4:    blocks [0,16)  : linear-space LSE forward (4 batches/wave) -> logZ
//                blocks [16,32) : Viterbi max-plus forward (4 batches/wave) -> va, last
//      Cross-lane via DPP + permlane swaps (VALU). 4 independent batch-chains
//      interleaved per wave to fill dependency stalls (r5: 1 chain = 385cyc/step,
//      issue only ~110 -> interleave 4 streams to approach issue-bound).
//   3) bp_extract: bp[b][t][k] = argmax_j(va[t-1][j]+trans[j][k])
//   4) backtrace: log-depth composition scan -> preds; + seq score -> ll
//
// ws layout (bytes):
//   pot : 0         4MB (+4KB pad: prefetch overshoot to t<=526)
//   va  : 4198400   4MB (+4KB pad)
//   bp  : 8396800   1MB
//   logZ: 9445376   256B
//   last: 9445632   256B

#define TT 512
#define KK 32
#define HH 768
#define NB 64

#define WS_POT 0
#define WS_VA  4198400
#define WS_BP  8396800
#define WS_LOGZ 9445376
#define WS_LAST 9445632

// ---------------- cross-lane primitives (VALU-speed) ----------------
template <int CTRL>
__device__ __forceinline__ float dppx(float x) {
  return __int_as_float(__builtin_amdgcn_update_dpp(
      0, __float_as_int(x), CTRL, 0xF, 0xF, true));
}

typedef unsigned int uint2v __attribute__((ext_vector_type(2)));

#if __has_builtin(__builtin_amdgcn_permlane16_swap)
__device__ __forceinline__ float xor16f(float x) {
  const unsigned xu = __float_as_uint(x);
  const uint2v q = __builtin_amdgcn_permlane16_swap(xu, xu, false, false);
  return __uint_as_float(q.x ^ q.y ^ xu);   // x[lane^16], direction-agnostic
}
#else
__device__ __forceinline__ float xor16f(float x) {
  return __int_as_float(__builtin_amdgcn_ds_swizzle(__float_as_int(x), 0x401F));
}
#endif

#if __has_builtin(__builtin_amdgcn_permlane32_swap)
__device__ __forceinline__ float xor32f(float x) {
  const unsigned xu = __float_as_uint(x);
  const uint2v q = __builtin_amdgcn_permlane32_swap(xu, xu, false, false);
  return __uint_as_float(q.x ^ q.y ^ xu);   // x[lane^32]
}
#else
__device__ __forceinline__ float xor32f(float x) { return __shfl_xor(x, 32, 64); }
#endif

__device__ __forceinline__ float redmax32(float v) {
  v = fmaxf(v, dppx<0xB1>(v));
  v = fmaxf(v, dppx<0x4E>(v));
  v = fmaxf(v, dppx<0x141>(v));
  v = fmaxf(v, dppx<0x128>(v));
  v = fmaxf(v, xor16f(v));
  return v;
}
__device__ __forceinline__ float redsum32(float v) {
  v += dppx<0xB1>(v);
  v += dppx<0x4E>(v);
  v += dppx<0x141>(v);
  v += dppx<0x128>(v);
  v += xor16f(v);
  return v;
}

__device__ __forceinline__ int gmap(int m) {
  return ((m & 1) ? 1 : 0) ^ ((m & 2) ? 2 : 0) ^ ((m & 4) ? 7 : 0) ^ ((m & 8) ? 8 : 0);
}

#define REPL_TREE(A)                                            \
  A[1] = dppx<0xB1>(A[0]);                                      \
  _Pragma("unroll") for (int p = 0; p < 2; ++p) A[2 + p] = dppx<0x4E>(A[p]);  \
  _Pragma("unroll") for (int p = 0; p < 4; ++p) A[4 + p] = dppx<0x141>(A[p]); \
  _Pragma("unroll") for (int p = 0; p < 8; ++p) A[8 + p] = dppx<0x128>(A[p]);

// one LSE step: returns sum_j a[j]*E[j][k] (full 32-j, both halves combined)
__device__ __forceinline__ float repl_dot(float a, const float* etrx, int jh) {
  float A[16];
  const float u16 = xor16f(a);
  A[0] = jh ? u16 : a;
  REPL_TREE(A)
  float d0 = 0.f, d1 = 0.f, d2 = 0.f, d3 = 0.f;
#pragma unroll
  for (int p = 0; p < 4; ++p) {
    d0 += A[4 * p + 0] * etrx[4 * p + 0];
    d1 += A[4 * p + 1] * etrx[4 * p + 1];
    d2 += A[4 * p + 2] * etrx[4 * p + 2];
    d3 += A[4 * p + 3] * etrx[4 * p + 3];
  }
  float part = (d0 + d1) + (d2 + d3);
  return part + xor32f(part);
}

// one Viterbi step: returns max_j(a[j]+tr[j][k])
__device__ __forceinline__ float repl_maxplus(float a, const float* trx, int jh) {
  float A[16];
  const float u16 = xor16f(a);
  A[0] = jh ? u16 : a;
  REPL_TREE(A)
  float s_[16];
#pragma unroll
  for (int m = 0; m < 16; ++m) s_[m] = A[m] + trx[m];
  const float m0 = fmaxf(fmaxf(s_[0], s_[1]), fmaxf(s_[2], s_[3]));
  const float m1 = fmaxf(fmaxf(s_[4], s_[5]), fmaxf(s_[6], s_[7]));
  const float m2 = fmaxf(fmaxf(s_[8], s_[9]), fmaxf(s_[10], s_[11]));
  const float m3 = fmaxf(fmaxf(s_[12], s_[13]), fmaxf(s_[14], s_[15]));
  const float part = fmaxf(fmaxf(m0, m1), fmaxf(m2, m3));
  return fmaxf(part, xor32f(part));
}

// ---------------------------------------------------------------- GEMM ------
__global__ __launch_bounds__(256) void gemm_pot(const float* __restrict__ x,
                                                const float* __restrict__ W,
                                                const float* __restrict__ bias,
                                                float* __restrict__ pot) {
  __shared__ float4 xs4[64][16];
  __shared__ float4 wt4[32][16];
  const int tid = threadIdx.x;
  const int row0 = blockIdx.x * 64;
  const int cg = tid & 15;
  const int rg = tid >> 4;
  const int c0 = cg * 2;
  float acc[4][2] = {{0.f, 0.f}, {0.f, 0.f}, {0.f, 0.f}, {0.f, 0.f}};

  for (int h0 = 0; h0 < HH; h0 += 64) {
#pragma unroll
    for (int p = 0; p < 4; ++p) {
      const int fi = tid + p * 256;
      const int r = fi >> 4, s = fi & 15;
      const float4 v = *(const float4*)(&x[(size_t)(row0 + r) * HH + h0 + s * 4]);
      xs4[r][s ^ ((r >> 2) & 3)] = v;
    }
    {
      const int c = tid & 31;
      const int hb = (tid >> 5) * 8;
      float* wf = (float*)(&wt4[0][0]);
#pragma unroll
      for (int i2 = 0; i2 < 8; ++i2) {
        const int hh = hb + i2;
        const int slot = (hh >> 2) ^ ((c >> 1) & 15);
        wf[c * 64 + slot * 4 + (hh & 3)] = W[(size_t)(h0 + hh) * KK + c];
      }
    }
    __syncthreads();
#pragma unroll
    for (int s = 0; s < 16; ++s) {
      float4 xv[4];
#pragma unroll
      for (int i = 0; i < 4; ++i) xv[i] = xs4[rg * 4 + i][s ^ (rg & 3)];
      const float4 wv0 = wt4[c0][s ^ cg];
      const float4 wv1 = wt4[c0 + 1][s ^ cg];
#pragma unroll
      for (int i = 0; i < 4; ++i) {
        acc[i][0] += xv[i].x * wv0.x + xv[i].y * wv0.y + xv[i].z * wv0.z + xv[i].w * wv0.w;
        acc[i][1] += xv[i].x * wv1.x + xv[i].y * wv1.y + xv[i].z * wv1.z + xv[i].w * wv1.w;
      }
    }
    __syncthreads();
  }
#pragma unroll
  for (int i = 0; i < 4; ++i) {
    const int row = row0 + rg * 4 + i;
    float2 o = make_float2(acc[i][0] + bias[c0], acc[i][1] + bias[c0 + 1]);
    *(float2*)(&pot[(size_t)row * KK + c0]) = o;
  }
}

// ---------------------------------------------------------------- scan4 -----
// grid 32 x 64. 4 batches per wave, chains interleaved.
__global__ __launch_bounds__(64) void scan4(const float* __restrict__ pot,
                                            const int* __restrict__ lens,
                                            const float* __restrict__ trans,
                                            float* __restrict__ va,
                                            float* __restrict__ logZ,
                                            int* __restrict__ last) {
  const int lane = threadIdx.x;
  const int k = lane & 31;
  const int jh = lane >> 5;
  const bool is_lse = (blockIdx.x < 16);
  const int b0 = (is_lse ? blockIdx.x : blockIdx.x - 16) * 4;

  int len[4];
#pragma unroll
  for (int q = 0; q < 4; ++q) len[q] = lens[b0 + q];
  const int maxlen = max(max(len[0], len[1]), max(len[2], len[3]));
  const float* pp[4];
#pragma unroll
  for (int q = 0; q < 4; ++q) pp[q] = pot + (size_t)(b0 + q) * (TT * KK) + k;

  if (is_lse) {
    // ---------- linear-space logsumexp forward, 4 batches ----------
    float etrx[16];
#pragma unroll
    for (int m = 0; m < 16; ++m)
      etrx[m] = __expf(trans[((k ^ gmap(m) ^ (jh << 4)) << 5) + k]);
    float a[4], alog[4];
#pragma unroll
    for (int q = 0; q < 4; ++q) {
      const float a0 = pp[q][0];
      const float M0 = redmax32(a0);
      a[q] = __expf(a0 - M0);
      alog[q] = M0;
    }
    float ep[4][8], en[4][8];
#pragma unroll
    for (int q = 0; q < 4; ++q)
#pragma unroll
      for (int i = 0; i < 8; ++i) ep[q][i] = __expf(pp[q][(size_t)(1 + i) * KK]);

    for (int tb = 1; tb < maxlen; tb += 8) {
#pragma unroll
      for (int q = 0; q < 4; ++q)
#pragma unroll
        for (int i = 0; i < 8; ++i) en[q][i] = pp[q][(size_t)(tb + 8 + i) * KK];
#pragma unroll
      for (int i = 0; i < 8; ++i) {
        const int t = tb + i;
        if (t >= maxlen) break;
#pragma unroll
        for (int q = 0; q < 4; ++q) {
          const float anew = repl_dot(a[q], etrx, jh) * ep[q][i];
          a[q] = (t < len[q]) ? anew : a[q];
        }
        if ((t & 3) == 0) {                    // renorm every 4 steps
#pragma unroll
          for (int q = 0; q < 4; ++q) {
            const float mx = redmax32(a[q]);
            alog[q] += __logf(mx);
            a[q] *= __builtin_amdgcn_rcpf(mx);
          }
        }
      }
#pragma unroll
      for (int q = 0; q < 4; ++q)
#pragma unroll
        for (int i = 0; i < 8; ++i) ep[q][i] = __expf(en[q][i]);
    }
#pragma unroll
    for (int q = 0; q < 4; ++q) {
      const float ssum = redsum32(a[q]);
      if (lane == 0) logZ[b0 + q] = alog[q] + __logf(ssum);
    }
  } else {
    // ---------- Viterbi max-plus forward, 4 batches ----------
    float trx[16];
#pragma unroll
    for (int m = 0; m < 16; ++m)
      trx[m] = trans[((k ^ gmap(m) ^ (jh << 4)) << 5) + k];
    float a[4];
    float* vap[4];
#pragma unroll
    for (int q = 0; q < 4; ++q) {
      a[q] = pp[q][0];
      vap[q] = va + (size_t)(b0 + q) * (TT * KK) + k;
      if (lane < 32) vap[q][0] = a[q];
    }
    float pb[4][8], pn[4][8];
#pragma unroll
    for (int q = 0; q < 4; ++q)
#pragma unroll
      for (int i = 0; i < 8; ++i) pb[q][i] = pp[q][(size_t)(1 + i) * KK];

    for (int tb = 1; tb < maxlen; tb += 8) {
#pragma unroll
      for (int q = 0; q < 4; ++q)
#pragma unroll
        for (int i = 0; i < 8; ++i) pn[q][i] = pp[q][(size_t)(tb + 8 + i) * KK];
#pragma unroll
      for (int i = 0; i < 8; ++i) {
        const int t = tb + i;
        if (t >= maxlen) break;
#pragma unroll
        for (int q = 0; q < 4; ++q) {
          const float anew = repl_maxplus(a[q], trx, jh) + pb[q][i];
          a[q] = (t < len[q]) ? anew : a[q];
          if (lane < 32) vap[q][(size_t)t * KK] = a[q];
        }
      }
#pragma unroll
      for (int q = 0; q < 4; ++q)
#pragma unroll
        for (int i = 0; i < 8; ++i) pb[q][i] = pn[q][i];
    }
#pragma unroll
    for (int q = 0; q < 4; ++q) {
      float v = a[q];
      int idx = k;
#pragma unroll
      for (int mm = 16; mm >= 1; mm >>= 1) {
        const float vo = __shfl_xor(v, mm, 32);
        const int io = __shfl_xor(idx, mm, 32);
        if (vo > v || (vo == v && io < idx)) { v = vo; idx = io; }
      }
      if (lane == 0) last[b0 + q] = idx;
    }
  }
}

// ----------------------------------------------------------- bp extract -----
__global__ __launch_bounds__(256) void bp_extract(const float* __restrict__ va,
                                                  const float* __restrict__ trans,
                                                  unsigned char* __restrict__ bp) {
  const int b = blockIdx.x >> 3;
  const int tbase = (blockIdx.x & 7) * 64;
  const int k = threadIdx.x & 31;
  const int ts = threadIdx.x >> 5;
  float tr[32];
#pragma unroll
  for (int j = 0; j < 32; ++j) tr[j] = trans[j * KK + k];
#pragma unroll
  for (int it = 0; it < 8; ++it) {
    const int t = tbase + it * 8 + ts;
    if (t < 1) continue;
    const float* row = va + ((size_t)b * TT + (t - 1)) * KK;
    float best = row[0] + tr[0];
    int bi = 0;
#pragma unroll
    for (int j = 1; j < 32; ++j) {
      const float s = row[j] + tr[j];
      if (s > best) { best = s; bi = j; }
    }
    bp[((size_t)b * TT + t) * KK + k] = (unsigned char)bi;
  }
}

// ------------------------------------------------------------- backtrace ----
__global__ __launch_bounds__(256) void backtrace_kernel(
    const unsigned char* __restrict__ bp, const int* __restrict__ lens,
    const int* __restrict__ last, const float* __restrict__ pot,
    const int* __restrict__ y, const float* __restrict__ trans,
    const float* __restrict__ logZ, float* __restrict__ out) {
  __shared__ unsigned char Ls[32736];
  __shared__ unsigned char sA[512], sB[512];
  __shared__ float red[256];
  const int b = blockIdx.x, tid = threadIdx.x;
  const int len = lens[b];

  for (int i = tid; i < TT * KK; i += 256) {
    const int t = i >> 5, k = i & 31;
    Ls[i] = (t >= 1 && t < len) ? bp[((size_t)b * TT + t) * KK + k] : (unsigned char)k;
  }
  __syncthreads();

  int off_prev = 0, cnt = 512;
  for (int l = 1; l <= 9; ++l) {
    const int off = 32 * (1024 - (1024 >> l));
    const int n = cnt >> 1;
    for (int i = tid; i < n * 32; i += 256) {
      const int m = i >> 5, k = i & 31;
      const int inner = Ls[off_prev + (2 * m + 1) * 32 + k];
      Ls[off + i] = Ls[off_prev + (2 * m) * 32 + inner];
    }
    __syncthreads();
    off_prev = off;
    cnt = n;
  }

  if (tid == 0) sA[0] = (unsigned char)last[b];
  __syncthreads();

  unsigned char* cur = sA;
  unsigned char* nxt = sB;
  int c2 = 1;
  for (int l = 9; l >= 1; --l) {
    const int offm = 32 * (1024 - (1024 >> (l - 1)));
    for (int i = tid; i < c2; i += 256) {
      const unsigned char s = cur[i];
      nxt[2 * i + 1] = s;
      nxt[2 * i] = Ls[offm + (2 * i + 1) * 32 + s];
    }
    __syncthreads();
    unsigned char* tmp = cur; cur = nxt; nxt = tmp;
    c2 <<= 1;
  }

  for (int t = tid; t < TT; t += 256)
    out[NB + (size_t)b * TT + t] = (t < len) ? (float)cur[t] : 0.f;

  float acc = 0.f;
  for (int t = tid; t < TT; t += 256) {
    const int yt = y[b * TT + t];
    if (t < len) acc += pot[((size_t)b * TT + t) * KK + yt];
    if (t < len - 1) acc += trans[yt * KK + y[b * TT + t + 1]];
  }
  red[tid] = acc;
  __syncthreads();
  for (int s = 128; s >= 1; s >>= 1) {
    if (tid < s) red[tid] += red[tid + s];
    __syncthreads();
  }
  if (tid == 0) out[b] = red[0] - logZ[b];
}

// ------------------------------------------------------------------ launch --
extern "C" void kernel_launch(void* const* d_in, const int* in_sizes, int n_in,
                              void* d_out, int out_size, void* d_ws, size_t ws_size,
                              hipStream_t stream) {
  const float* x = (const float*)d_in[0];
  const int* y = (const int*)d_in[1];
  const int* lens = (const int*)d_in[2];
  const float* W = (const float*)d_in[3];
  const float* bias = (const float*)d_in[4];
  const float* trans = (const float*)d_in[5];
  float* out = (float*)d_out;
  char* ws = (char*)d_ws;
  float* pot = (float*)(ws + WS_POT);
  float* va = (float*)(ws + WS_VA);
  unsigned char* bp = (unsigned char*)(ws + WS_BP);
  float* logZ = (float*)(ws + WS_LOGZ);
  int* last = (int*)(ws + WS_LAST);

  gemm_pot<<<512, 256, 0, stream>>>(x, W, bias, pot);
  scan4<<<32, 64, 0, stream>>>(pot, lens, trans, va, logZ, last);
  bp_extract<<<512, 256, 0, stream>>>(va, trans, bp);
  backtrace_kernel<<<64, 256, 0, stream>>>(bp, lens, last, pot, y, trans, logZ, out);
}

// Round 7
// 152.640 us; speedup vs baseline: 2.2127x; 2.2127x over previous
//
#include <hip/hip_runtime.h>
#include <hip/hip_bf16.h>
#include <stdint.h>

// CRF entity layer: B=64, T=512, H=768, K=32
//   1) gemm_pot: pot[b][t][k] = x[b,t,:]·W[:,k] + b[k]
//   2) scan2:    blocks [0,64)  : linear-space LSE forward -> logZ[b]
//                blocks [64,128): Viterbi max-plus forward -> va, last[b]
//      1 batch/wave. Cross-lane strictly VALU: DPP tree + inline-asm
//      v_permlane16/32_swap_b32 (r5's __has_builtin guard may have silently
//      fallen back to ds_swizzle/bpermute = 2x ~110cyc LDS ops on the chain).
//   3) bp_extract: bp[b][t][k] = argmax_j(va[t-1][j]+trans[j][k])
//   4) backtrace: log-depth composition scan -> preds; + seq score -> ll
//
// ws layout (bytes):
//   pot : 0         4MB (+4KB pad: prefetch overshoot to t<=526)
//   va  : 4198400   4MB (+4KB pad)
//   bp  : 8396800   1MB
//   logZ: 9445376   256B
//   last: 9445632   256B

#define TT 512
#define KK 32
#define HH 768
#define NB 64

#define WS_POT 0
#define WS_VA  4198400
#define WS_BP  8396800
#define WS_LOGZ 9445376
#define WS_LAST 9445632

// ---------------- cross-lane primitives (VALU-speed, asm-guaranteed) --------
template <int CTRL>
__device__ __forceinline__ float dppx(float x) {
  return __int_as_float(__builtin_amdgcn_update_dpp(
      0, __float_as_int(x), CTRL, 0xF, 0xF, true));
}

// x[lane^16]: v_permlane16_swap_b32 exchanges odd 16-rows of D with even
// 16-rows of S. With D=S=x, {newD,newS} = {own, partner} per lane, so
// newD^newS^x = x[lane^16] regardless of pairing direction.
__device__ __forceinline__ float xor16f(float x) {
  float d = x, s = x;
  asm volatile("v_permlane16_swap_b32 %0, %1" : "+v"(d), "+v"(s));
  return __uint_as_float(__float_as_uint(d) ^ __float_as_uint(s) ^ __float_as_uint(x));
}
// x[lane^32]: same trick with the 32-row swap.
__device__ __forceinline__ float xor32f(float x) {
  float d = x, s = x;
  asm volatile("v_permlane32_swap_b32 %0, %1" : "+v"(d), "+v"(s));
  return __uint_as_float(__float_as_uint(d) ^ __float_as_uint(s) ^ __float_as_uint(x));
}

__device__ __forceinline__ float redmax32(float v) {
  v = fmaxf(v, dppx<0xB1>(v));
  v = fmaxf(v, dppx<0x4E>(v));
  v = fmaxf(v, dppx<0x141>(v));
  v = fmaxf(v, dppx<0x128>(v));
  v = fmaxf(v, xor16f(v));
  return v;
}
__device__ __forceinline__ float redsum32(float v) {
  v += dppx<0xB1>(v);
  v += dppx<0x4E>(v);
  v += dppx<0x141>(v);
  v += dppx<0x128>(v);
  v += xor16f(v);
  return v;
}

__device__ __forceinline__ int gmap(int m) {
  return ((m & 1) ? 1 : 0) ^ ((m & 2) ? 2 : 0) ^ ((m & 4) ? 7 : 0) ^ ((m & 8) ? 8 : 0);
}

// A[m] = a_from_lane(k ^ G[m]); 15 v_mov_dpp, depth 4.
#define REPL_TREE(A)                                            \
  A[1] = dppx<0xB1>(A[0]);                                      \
  _Pragma("unroll") for (int p = 0; p < 2; ++p) A[2 + p] = dppx<0x4E>(A[p]);  \
  _Pragma("unroll") for (int p = 0; p < 4; ++p) A[4 + p] = dppx<0x141>(A[p]); \
  _Pragma("unroll") for (int p = 0; p < 8; ++p) A[8 + p] = dppx<0x128>(A[p]);

// ---------------------------------------------------------------- GEMM ------
__global__ __launch_bounds__(256) void gemm_pot(const float* __restrict__ x,
                                                const float* __restrict__ W,
                                                const float* __restrict__ bias,
                                                float* __restrict__ pot) {
  __shared__ float4 xs4[64][16];
  __shared__ float4 wt4[32][16];
  const int tid = threadIdx.x;
  const int row0 = blockIdx.x * 64;
  const int cg = tid & 15;
  const int rg = tid >> 4;
  const int c0 = cg * 2;
  float acc[4][2] = {{0.f, 0.f}, {0.f, 0.f}, {0.f, 0.f}, {0.f, 0.f}};

  for (int h0 = 0; h0 < HH; h0 += 64) {
#pragma unroll
    for (int p = 0; p < 4; ++p) {
      const int fi = tid + p * 256;
      const int r = fi >> 4, s = fi & 15;
      const float4 v = *(const float4*)(&x[(size_t)(row0 + r) * HH + h0 + s * 4]);
      xs4[r][s ^ ((r >> 2) & 3)] = v;
    }
    {
      const int c = tid & 31;
      const int hb = (tid >> 5) * 8;
      float* wf = (float*)(&wt4[0][0]);
#pragma unroll
      for (int i2 = 0; i2 < 8; ++i2) {
        const int hh = hb + i2;
        const int slot = (hh >> 2) ^ ((c >> 1) & 15);
        wf[c * 64 + slot * 4 + (hh & 3)] = W[(size_t)(h0 + hh) * KK + c];
      }
    }
    __syncthreads();
#pragma unroll
    for (int s = 0; s < 16; ++s) {
      float4 xv[4];
#pragma unroll
      for (int i = 0; i < 4; ++i) xv[i] = xs4[rg * 4 + i][s ^ (rg & 3)];
      const float4 wv0 = wt4[c0][s ^ cg];
      const float4 wv1 = wt4[c0 + 1][s ^ cg];
#pragma unroll
      for (int i = 0; i < 4; ++i) {
        acc[i][0] += xv[i].x * wv0.x + xv[i].y * wv0.y + xv[i].z * wv0.z + xv[i].w * wv0.w;
        acc[i][1] += xv[i].x * wv1.x + xv[i].y * wv1.y + xv[i].z * wv1.z + xv[i].w * wv1.w;
      }
    }
    __syncthreads();
  }
#pragma unroll
  for (int i = 0; i < 4; ++i) {
    const int row = row0 + rg * 4 + i;
    float2 o = make_float2(acc[i][0] + bias[c0], acc[i][1] + bias[c0 + 1]);
    *(float2*)(&pot[(size_t)row * KK + c0]) = o;
  }
}

// ---------------------------------------------------------------- scan2 -----
// grid 128 x 64. 1 batch per wave. lane = jh*32 + k. Half jh covers
// j = k ^ G[m] ^ (jh<<4), m=0..15.
__global__ __launch_bounds__(64) void scan2(const float* __restrict__ pot,
                                            const int* __restrict__ lens,
                                            const float* __restrict__ trans,
                                            float* __restrict__ va,
                                            float* __restrict__ logZ,
                                            int* __restrict__ last) {
  const int lane = threadIdx.x;
  const int k = lane & 31;
  const int jh = lane >> 5;
  const bool is_lse = (blockIdx.x < 64);
  const int b = is_lse ? blockIdx.x : blockIdx.x - 64;
  const int len = lens[b];
  const float* pp = pot + (size_t)b * (TT * KK) + k;

  if (is_lse) {
    // ---------- linear-space logsumexp forward ----------
    float etrx[16];
#pragma unroll
    for (int m = 0; m < 16; ++m)
      etrx[m] = __expf(trans[((k ^ gmap(m) ^ (jh << 4)) << 5) + k]);
    const float a0 = pp[0];
    const float M0 = redmax32(a0);
    float a = __expf(a0 - M0);
    float alog = M0;
    float ep[8], en[8];
#pragma unroll
    for (int i = 0; i < 8; ++i) ep[i] = __expf(pp[(size_t)(1 + i) * KK]);
    for (int tb = 1; tb < len; tb += 8) {
#pragma unroll
      for (int i = 0; i < 8; ++i) en[i] = pp[(size_t)(tb + 8 + i) * KK];
#pragma unroll
      for (int i = 0; i < 8; ++i) {
        const int t = tb + i;
        if (t >= len) break;
        float A[16];
        const float u16 = xor16f(a);
        A[0] = jh ? u16 : a;
        REPL_TREE(A)
        float d0 = 0.f, d1 = 0.f, d2 = 0.f, d3 = 0.f;
#pragma unroll
        for (int p = 0; p < 4; ++p) {
          d0 += A[4 * p + 0] * etrx[4 * p + 0];
          d1 += A[4 * p + 1] * etrx[4 * p + 1];
          d2 += A[4 * p + 2] * etrx[4 * p + 2];
          d3 += A[4 * p + 3] * etrx[4 * p + 3];
        }
        float part = (d0 + d1) + (d2 + d3);
        a = (part + xor32f(part)) * ep[i];
        if ((t & 7) == 0) {                   // renorm every 8 steps (f32-safe)
          const float mx = redmax32(a);
          alog += __logf(mx);
          a *= __builtin_amdgcn_rcpf(mx);
        }
      }
#pragma unroll
      for (int i = 0; i < 8; ++i) ep[i] = __expf(en[i]);
    }
    const float ssum = redsum32(a);
    if (lane == 0) logZ[b] = alog + __logf(ssum);
  } else {
    // ---------- Viterbi max-plus forward ----------
    float trx[16];
#pragma unroll
    for (int m = 0; m < 16; ++m)
      trx[m] = trans[((k ^ gmap(m) ^ (jh << 4)) << 5) + k];
    float a = pp[0];
    float* vap = va + (size_t)b * (TT * KK) + k;
    if (lane < 32) vap[0] = a;
    float pb[8], pn[8];
#pragma unroll
    for (int i = 0; i < 8; ++i) pb[i] = pp[(size_t)(1 + i) * KK];
    for (int tb = 1; tb < len; tb += 8) {
#pragma unroll
      for (int i = 0; i < 8; ++i) pn[i] = pp[(size_t)(tb + 8 + i) * KK];
#pragma unroll
      for (int i = 0; i < 8; ++i) {
        const int t = tb + i;
        if (t >= len) break;
        float A[16];
        const float u16 = xor16f(a);
        A[0] = jh ? u16 : a;
        REPL_TREE(A)
        float s_[16];
#pragma unroll
        for (int m = 0; m < 16; ++m) s_[m] = A[m] + trx[m];
        const float m0 = fmaxf(fmaxf(s_[0], s_[1]), fmaxf(s_[2], s_[3]));
        const float m1 = fmaxf(fmaxf(s_[4], s_[5]), fmaxf(s_[6], s_[7]));
        const float m2 = fmaxf(fmaxf(s_[8], s_[9]), fmaxf(s_[10], s_[11]));
        const float m3 = fmaxf(fmaxf(s_[12], s_[13]), fmaxf(s_[14], s_[15]));
        const float part = fmaxf(fmaxf(m0, m1), fmaxf(m2, m3));
        a = fmaxf(part, xor32f(part)) + pb[i];
        if (lane < 32) vap[(size_t)t * KK] = a;
      }
#pragma unroll
      for (int i = 0; i < 8; ++i) pb[i] = pn[i];
    }
    // argmax over k (first-index tiebreak)
    float v = a;
    int idx = k;
#pragma unroll
    for (int mm = 16; mm >= 1; mm >>= 1) {
      const float vo = __shfl_xor(v, mm, 32);
      const int io = __shfl_xor(idx, mm, 32);
      if (vo > v || (vo == v && io < idx)) { v = vo; idx = io; }
    }
    if (lane == 0) last[b] = idx;
  }
}

// ----------------------------------------------------------- bp extract -----
__global__ __launch_bounds__(256) void bp_extract(const float* __restrict__ va,
                                                  const float* __restrict__ trans,
                                                  unsigned char* __restrict__ bp) {
  const int b = blockIdx.x >> 3;
  const int tbase = (blockIdx.x & 7) * 64;
  const int k = threadIdx.x & 31;
  const int ts = threadIdx.x >> 5;
  float tr[32];
#pragma unroll
  for (int j = 0; j < 32; ++j) tr[j] = trans[j * KK + k];
#pragma unroll
  for (int it = 0; it < 8; ++it) {
    const int t = tbase + it * 8 + ts;
    if (t < 1) continue;
    const float* row = va + ((size_t)b * TT + (t - 1)) * KK;
    float best = row[0] + tr[0];
    int bi = 0;
#pragma unroll
    for (int j = 1; j < 32; ++j) {
      const float s = row[j] + tr[j];
      if (s > best) { best = s; bi = j; }
    }
    bp[((size_t)b * TT + t) * KK + k] = (unsigned char)bi;
  }
}

// ------------------------------------------------------------- backtrace ----
__global__ __launch_bounds__(256) void backtrace_kernel(
    const unsigned char* __restrict__ bp, const int* __restrict__ lens,
    const int* __restrict__ last, const float* __restrict__ pot,
    const int* __restrict__ y, const float* __restrict__ trans,
    const float* __restrict__ logZ, float* __restrict__ out) {
  __shared__ unsigned char Ls[32736];
  __shared__ unsigned char sA[512], sB[512];
  __shared__ float red[256];
  const int b = blockIdx.x, tid = threadIdx.x;
  const int len = lens[b];

  for (int i = tid; i < TT * KK; i += 256) {
    const int t = i >> 5, k = i & 31;
    Ls[i] = (t >= 1 && t < len) ? bp[((size_t)b * TT + t) * KK + k] : (unsigned char)k;
  }
  __syncthreads();

  int off_prev = 0, cnt = 512;
  for (int l = 1; l <= 9; ++l) {
    const int off = 32 * (1024 - (1024 >> l));
    const int n = cnt >> 1;
    for (int i = tid; i < n * 32; i += 256) {
      const int m = i >> 5, k = i & 31;
      const int inner = Ls[off_prev + (2 * m + 1) * 32 + k];
      Ls[off + i] = Ls[off_prev + (2 * m) * 32 + inner];
    }
    __syncthreads();
    off_prev = off;
    cnt = n;
  }

  if (tid == 0) sA[0] = (unsigned char)last[b];
  __syncthreads();

  unsigned char* cur = sA;
  unsigned char* nxt = sB;
  int c2 = 1;
  for (int l = 9; l >= 1; --l) {
    const int offm = 32 * (1024 - (1024 >> (l - 1)));
    for (int i = tid; i < c2; i += 256) {
      const unsigned char s = cur[i];
      nxt[2 * i + 1] = s;
      nxt[2 * i] = Ls[offm + (2 * i + 1) * 32 + s];
    }
    __syncthreads();
    unsigned char* tmp = cur; cur = nxt; nxt = tmp;
    c2 <<= 1;
  }

  for (int t = tid; t < TT; t += 256)
    out[NB + (size_t)b * TT + t] = (t < len) ? (float)cur[t] : 0.f;

  float acc = 0.f;
  for (int t = tid; t < TT; t += 256) {
    const int yt = y[b * TT + t];
    if (t < len) acc += pot[((size_t)b * TT + t) * KK + yt];
    if (t < len - 1) acc += trans[yt * KK + y[b * TT + t + 1]];
  }
  red[tid] = acc;
  __syncthreads();
  for (int s = 128; s >= 1; s >>= 1) {
    if (tid < s) red[tid] += red[tid + s];
    __syncthreads();
  }
  if (tid == 0) out[b] = red[0] - logZ[b];
}

// ------------------------------------------------------------------ launch --
extern "C" void kernel_launch(void* const* d_in, const int* in_sizes, int n_in,
                              void* d_out, int out_size, void* d_ws, size_t ws_size,
                              hipStream_t stream) {
  const float* x = (const float*)d_in[0];
  const int* y = (const int*)d_in[1];
  const int* lens = (const int*)d_in[2];
  const float* W = (const float*)d_in[3];
  const float* bias = (const float*)d_in[4];
  const float* trans = (const float*)d_in[5];
  float* out = (float*)d_out;
  char* ws = (char*)d_ws;
  float* pot = (float*)(ws + WS_POT);
  float* va = (float*)(ws + WS_VA);
  unsigned char* bp = (unsigned char*)(ws + WS_BP);
  float* logZ = (float*)(ws + WS_LOGZ);
  int* last = (int*)(ws + WS_LAST);

  gemm_pot<<<512, 256, 0, stream>>>(x, W, bias, pot);
  scan2<<<128, 64, 0, stream>>>(pot, lens, trans, va, logZ, last);
  bp_extract<<<512, 256, 0, stream>>>(va, trans, bp);
  backtrace_kernel<<<64, 256, 0, stream>>>(bp, lens, last, pot, y, trans, logZ, out);
}